// Round 1
// baseline (390.045 us; speedup 1.0000x reference)
//
#include <hip/hip_runtime.h>

#define C 16
#define NIMG 24
#define H 96
#define W 192
#define PX (H*W)            // 18432 pixels per image
#define ROWS 3              // rows per attention block

// workspace float offsets
#define Q_OFF 0
#define K_OFF (NIMG*2*PX)                  // 884736
#define V_OFF (2*NIMG*2*PX)                // 1769472
#define X1_OFF (V_OFF + NIMG*C*PX)         // 8847360
// total floats: 15925248 (~63.7 MB)

__global__ __launch_bounds__(256)
void qkv_kernel(const float* __restrict__ x, long xn_s, long xc_s,
                const float* __restrict__ qw, const float* __restrict__ qb,
                const float* __restrict__ kw, const float* __restrict__ kb,
                const float* __restrict__ vw, const float* __restrict__ vb,
                float* __restrict__ Q, float* __restrict__ K, float* __restrict__ V)
{
    __shared__ float wq[2*C+2], wk[2*C+2], wv[C*C+C];
    int tid = threadIdx.x;
    if (tid < 2*C) { wq[tid] = qw[tid]; wk[tid] = kw[tid]; }
    if (tid < 2)   { wq[2*C+tid] = qb[tid]; wk[2*C+tid] = kb[tid]; }
    if (tid < C*C) wv[tid] = vw[tid];
    if (tid < C)   wv[C*C+tid] = vb[tid];
    __syncthreads();

    int id = blockIdx.x*256 + tid;        // 0 .. 442367
    int n  = id / PX;
    int p  = id - n*PX;
    const float* xp = x + (long)n*xn_s + p;

    float xv[C];
    #pragma unroll
    for (int c = 0; c < C; c++) xv[c] = xp[(long)c*xc_s];

    float q0 = wq[2*C], q1 = wq[2*C+1];
    float k0 = wk[2*C], k1 = wk[2*C+1];
    #pragma unroll
    for (int c = 0; c < C; c++) {
        q0 += wq[c]*xv[c];   q1 += wq[C+c]*xv[c];
        k0 += wk[c]*xv[c];   k1 += wk[C+c]*xv[c];
    }
    Q[(n*2+0)*PX + p] = q0;  Q[(n*2+1)*PX + p] = q1;
    K[(n*2+0)*PX + p] = k0;  K[(n*2+1)*PX + p] = k1;

    #pragma unroll
    for (int o = 0; o < C; o++) {
        float a = wv[C*C+o];
        #pragma unroll
        for (int c = 0; c < C; c++) a += wv[o*C+c]*xv[c];
        V[((long)n*C + o)*PX + p] = a;
    }
}

__global__ __launch_bounds__(192)
void attn_kernel(const float* __restrict__ Q, const float* __restrict__ K,
                 const float* __restrict__ V,
                 const float* __restrict__ xres, long xn_s, long xc_s,
                 float* __restrict__ out, long on_s, long oc_s,
                 const float* __restrict__ gamma_p)
{
    // k_row[r][j][o]: K channels o=0,1 at row (h0+r), col j  (for W-attention)
    // v_row[r][j][c]: V channels at row (h0+r), col j        (for W-attention)
    __shared__ __align__(16) float k_row[ROWS][W][2];
    __shared__ __align__(16) float v_row[ROWS][W][C];

    int bid = blockIdx.x;
    int n   = bid >> 5;            // /32 tiles
    int h0  = (bid & 31) * ROWS;
    int w   = threadIdx.x;         // 0..191

    const float* Qn = Q + (long)n*2*PX;
    const float* Kn = K + (long)n*2*PX;
    const float* Vn = V + (long)n*C*PX;

    // stage row K/V into LDS (one-time; write conflicts acceptable)
    #pragma unroll
    for (int r = 0; r < ROWS; r++) {
        k_row[r][w][0] = Kn[(0*H + h0+r)*W + w];
        k_row[r][w][1] = Kn[(1*H + h0+r)*W + w];
        #pragma unroll
        for (int c = 0; c < C; c++)
            v_row[r][w][c] = Vn[((long)c*H + (h0+r))*W + w];
    }

    float q0[ROWS], q1[ROWS];
    #pragma unroll
    for (int r = 0; r < ROWS; r++) {
        q0[r] = Qn[(0*H + h0+r)*W + w];
        q1[r] = Qn[(1*H + h0+r)*W + w];
    }
    __syncthreads();

    // ---- phase A: find max over all 288 energies (diag of H part masked) ----
    float m[ROWS];
    #pragma unroll
    for (int r = 0; r < ROWS; r++) m[r] = -3.0e38f;

    for (int j = 0; j < H; j++) {
        float kc0 = Kn[(0*H + j)*W + w];
        float kc1 = Kn[(1*H + j)*W + w];
        #pragma unroll
        for (int r = 0; r < ROWS; r++) {
            if (j != h0 + r) {
                float e = q0[r]*kc0 + q1[r]*kc1;
                m[r] = fmaxf(m[r], e);
            }
        }
    }
    #pragma unroll
    for (int r = 0; r < ROWS; r++) {
        float mm = m[r];
        for (int j = 0; j < W; j++) {
            float e = q0[r]*k_row[r][j][0] + q1[r]*k_row[r][j][1];
            mm = fmaxf(mm, e);
        }
        m[r] = mm;
    }

    // ---- phase B: exp + accumulate (unnormalized), normalize at end ----
    float s[ROWS];
    float acc[ROWS][C];
    #pragma unroll
    for (int r = 0; r < ROWS; r++) {
        s[r] = 0.0f;
        #pragma unroll
        for (int c = 0; c < C; c++) acc[r][c] = 0.0f;
    }

    // B1: H (column) part — V columns from global (coalesced over w, L2-hot)
    for (int j = 0; j < H; j++) {
        float kc0 = Kn[(0*H + j)*W + w];
        float kc1 = Kn[(1*H + j)*W + w];
        float vv[C];
        #pragma unroll
        for (int c = 0; c < C; c++) vv[c] = Vn[((long)c*H + j)*W + w];
        #pragma unroll
        for (int r = 0; r < ROWS; r++) {
            if (j != h0 + r) {
                float e = q0[r]*kc0 + q1[r]*kc1;
                float p = __expf(e - m[r]);
                s[r] += p;
                #pragma unroll
                for (int c = 0; c < C; c++) acc[r][c] += p*vv[c];
            }
        }
    }

    // B2: W (row) part — K/V from LDS, uniform broadcast reads
    #pragma unroll
    for (int r = 0; r < ROWS; r++) {
        float sr = s[r];
        for (int j = 0; j < W; j++) {
            float e = q0[r]*k_row[r][j][0] + q1[r]*k_row[r][j][1];
            float p = __expf(e - m[r]);
            sr += p;
            const float4* vp = reinterpret_cast<const float4*>(&v_row[r][j][0]);
            #pragma unroll
            for (int c4 = 0; c4 < 4; c4++) {
                float4 v4 = vp[c4];
                acc[r][c4*4+0] += p*v4.x;
                acc[r][c4*4+1] += p*v4.y;
                acc[r][c4*4+2] += p*v4.z;
                acc[r][c4*4+3] += p*v4.w;
            }
        }
        s[r] = sr;
    }

    // ---- epilogue: gamma*(acc/s) + x ----
    float g = gamma_p[0];
    #pragma unroll
    for (int r = 0; r < ROWS; r++) {
        float inv = 1.0f / s[r];
        #pragma unroll
        for (int c = 0; c < C; c++) {
            float res = g*(acc[r][c]*inv)
                      + xres[(long)n*xn_s + (long)c*xc_s + (h0+r)*W + w];
            out[(long)n*on_s + (long)c*oc_s + (h0+r)*W + w] = res;
        }
    }
}

extern "C" void kernel_launch(void* const* d_in, const int* in_sizes, int n_in,
                              void* d_out, int out_size, void* d_ws, size_t ws_size,
                              hipStream_t stream) {
    const float* cost = (const float*)d_in[0];   // (1,16,24,96,192)
    const float* q_w  = (const float*)d_in[1];
    const float* q_b  = (const float*)d_in[2];
    const float* k_w  = (const float*)d_in[3];
    const float* k_b  = (const float*)d_in[4];
    const float* v_w  = (const float*)d_in[5];
    const float* v_b  = (const float*)d_in[6];
    const float* gamma= (const float*)d_in[7];
    float* out = (float*)d_out;
    float* ws  = (float*)d_ws;

    float* Qb = ws + Q_OFF;
    float* Kb = ws + K_OFF;
    float* Vb = ws + V_OFF;
    float* X1 = ws + X1_OFF;

    const int qkv_blocks  = (NIMG*PX)/256;   // 1728
    const int attn_blocks = NIMG*(H/ROWS);   // 768

    // pass 1: x = cost_volume with layout [c][n][h][w] (c stride 24*PX, n stride PX)
    qkv_kernel<<<qkv_blocks, 256, 0, stream>>>(
        cost, (long)PX, (long)NIMG*PX,
        q_w, q_b, k_w, k_b, v_w, v_b, Qb, Kb, Vb);
    attn_kernel<<<attn_blocks, 192, 0, stream>>>(
        Qb, Kb, Vb,
        cost, (long)PX, (long)NIMG*PX,      // residual read
        X1, (long)C*PX, (long)PX,           // X1 layout [n][c][h][w]
        gamma);

    // pass 2: x = X1 ([n][c][h][w]); final out layout [c][n][h][w]
    qkv_kernel<<<qkv_blocks, 256, 0, stream>>>(
        X1, (long)C*PX, (long)PX,
        q_w, q_b, k_w, k_b, v_w, v_b, Qb, Kb, Vb);
    attn_kernel<<<attn_blocks, 192, 0, stream>>>(
        Qb, Kb, Vb,
        X1, (long)C*PX, (long)PX,
        out, (long)PX, (long)NIMG*PX,
        gamma);
}

// Round 2
// 364.757 us; speedup vs baseline: 1.0693x; 1.0693x over previous
//
#include <hip/hip_runtime.h>

#define C 16
#define NIMG 24
#define H 96
#define W 192
#define PX (H*W)            // 18432
#define ROWS 3
#define LOG2E 1.44269504088896f

// workspace float offsets
#define QP_OFF 0
#define KP_OFF (NIMG*PX*2)                      // 884736
#define VP_OFF (2*NIMG*PX*2)                    // 1769472
#define X1_OFF (VP_OFF + NIMG*PX*C)             // 8847360
#define CMAX_OFF (X1_OFF + NIMG*C*PX)           // 15925248
#define RMAX_OFF (CMAX_OFF + NIMG*2*W)          // +9216
// total ~15939072 floats (~63.8 MB)

__global__ __launch_bounds__(256)
void qkv_kernel(const float* __restrict__ x, long xn_s, long xc_s,
                const float* __restrict__ qw, const float* __restrict__ qb,
                const float* __restrict__ kw, const float* __restrict__ kb,
                const float* __restrict__ vw, const float* __restrict__ vb,
                float2* __restrict__ Qp, float2* __restrict__ Kp,
                float4* __restrict__ Vp)
{
    __shared__ float wq[2*C+2], wk[2*C+2], wv[C*C+C];
    int tid = threadIdx.x;
    if (tid < 2*C) { wq[tid] = qw[tid]; wk[tid] = kw[tid]; }
    if (tid < 2)   { wq[2*C+tid] = qb[tid]; wk[2*C+tid] = kb[tid]; }
    if (tid < C*C) wv[tid] = vw[tid];
    if (tid < C)   wv[C*C+tid] = vb[tid];
    __syncthreads();

    int id = blockIdx.x*256 + tid;        // 0 .. 442367
    int n  = id / PX;
    int p  = id - n*PX;
    const float* xp = x + (long)n*xn_s + p;

    float xv[C];
    #pragma unroll
    for (int c = 0; c < C; c++) xv[c] = xp[(long)c*xc_s];

    float q0 = wq[2*C], q1 = wq[2*C+1];
    float k0 = wk[2*C], k1 = wk[2*C+1];
    #pragma unroll
    for (int c = 0; c < C; c++) {
        q0 += wq[c]*xv[c];   q1 += wq[C+c]*xv[c];
        k0 += wk[c]*xv[c];   k1 += wk[C+c]*xv[c];
    }
    Qp[id] = make_float2(q0, q1);
    Kp[id] = make_float2(k0, k1);

    float vv[C];
    #pragma unroll
    for (int o = 0; o < C; o++) {
        float a = wv[C*C+o];
        #pragma unroll
        for (int c = 0; c < C; c++) a += wv[o*C+c]*xv[c];
        vv[o] = a;
    }
    long vbase = (long)id * 4;
    Vp[vbase+0] = make_float4(vv[0],  vv[1],  vv[2],  vv[3]);
    Vp[vbase+1] = make_float4(vv[4],  vv[5],  vv[6],  vv[7]);
    Vp[vbase+2] = make_float4(vv[8],  vv[9],  vv[10], vv[11]);
    Vp[vbase+3] = make_float4(vv[12], vv[13], vv[14], vv[15]);
}

// per-image column/row |K| maxima (for the softmax shift bound)
__global__ __launch_bounds__(192)
void stats_kernel(const float2* __restrict__ Kp,
                  float* __restrict__ cmax, float* __restrict__ rmax)
{
    int n = blockIdx.x;
    int tid = threadIdx.x;
    const float2* Kpn = Kp + n*PX;

    float c0 = 0.f, c1 = 0.f;
    for (int h = 0; h < H; h++) {
        float2 k = Kpn[h*W + tid];
        c0 = fmaxf(c0, fabsf(k.x));
        c1 = fmaxf(c1, fabsf(k.y));
    }
    cmax[n*2*W + tid]     = c0;
    cmax[n*2*W + W + tid] = c1;

    if (tid < H) {
        float r0 = 0.f, r1 = 0.f;
        for (int j = 0; j < W; j++) {
            float2 k = Kpn[tid*W + j];
            r0 = fmaxf(r0, fabsf(k.x));
            r1 = fmaxf(r1, fabsf(k.y));
        }
        rmax[n*2*H + tid]     = r0;
        rmax[n*2*H + H + tid] = r1;
    }
}

__global__ __launch_bounds__(192)
void attn_kernel(const float2* __restrict__ Qp, const float2* __restrict__ Kp,
                 const float4* __restrict__ Vp,
                 const float* __restrict__ cmax, const float* __restrict__ rmax,
                 const float* __restrict__ xres, long xn_s, long xc_s,
                 float* __restrict__ out, long on_s, long oc_s,
                 const float* __restrict__ gamma_p)
{
    int bid = blockIdx.x;
    int n   = bid >> 5;            // 32 row-tiles per image
    int h0  = (bid & 31) * ROWS;
    int w   = threadIdx.x;         // 0..191

    const float2* Qpn = Qp + n*PX;
    const float2* Kpn = Kp + n*PX;
    const float4* Vpn = Vp + (long)n*PX*4;

    // q (scaled to log2 domain) and softmax shift bound m
    float c0 = cmax[n*2*W + w], c1 = cmax[n*2*W + W + w];
    float2 q[ROWS];
    float  m[ROWS];
    #pragma unroll
    for (int r = 0; r < ROWS; r++) {
        float2 qq = Qpn[(h0+r)*W + w];
        q[r].x = qq.x * LOG2E;
        q[r].y = qq.y * LOG2E;
        float aq0 = fabsf(q[r].x), aq1 = fabsf(q[r].y);
        float r0 = rmax[n*2*H + h0+r], r1 = rmax[n*2*H + H + h0+r];
        m[r] = fmaxf(aq0*c0 + aq1*c1, aq0*r0 + aq1*r1);
    }

    float s[ROWS] = {0.f, 0.f, 0.f};
    float acc[ROWS][C] = {};

    // ---- column (H) part: coalesced reads, diag masked ----
    for (int j = 0; j < H; j++) {
        float2 k = Kpn[j*W + w];
        int vb = (j*W + w)*4;
        float4 v0 = Vpn[vb+0], v1 = Vpn[vb+1], v2 = Vpn[vb+2], v3 = Vpn[vb+3];
        #pragma unroll
        for (int r = 0; r < ROWS; r++) {
            float e = q[r].x*k.x + q[r].y*k.y;
            float p = __builtin_amdgcn_exp2f(e - m[r]);
            p = (j == h0 + r) ? 0.0f : p;
            s[r] += p;
            acc[r][0]  += p*v0.x; acc[r][1]  += p*v0.y; acc[r][2]  += p*v0.z; acc[r][3]  += p*v0.w;
            acc[r][4]  += p*v1.x; acc[r][5]  += p*v1.y; acc[r][6]  += p*v1.z; acc[r][7]  += p*v1.w;
            acc[r][8]  += p*v2.x; acc[r][9]  += p*v2.y; acc[r][10] += p*v2.z; acc[r][11] += p*v2.w;
            acc[r][12] += p*v3.x; acc[r][13] += p*v3.y; acc[r][14] += p*v3.z; acc[r][15] += p*v3.w;
        }
    }

    // ---- row (W) part: wave-uniform broadcast reads, unmasked ----
    #pragma unroll
    for (int r = 0; r < ROWS; r++) {
        const float2* kr = Kpn + (h0+r)*W;
        const float4* vr = Vpn + (long)(h0+r)*W*4;
        float sr = s[r];
        float qx = q[r].x, qy = q[r].y, mr = m[r];
        for (int j = 0; j < W; j++) {
            float2 k = kr[j];
            float e = qx*k.x + qy*k.y;
            float p = __builtin_amdgcn_exp2f(e - mr);
            sr += p;
            float4 v0 = vr[j*4+0], v1 = vr[j*4+1], v2 = vr[j*4+2], v3 = vr[j*4+3];
            acc[r][0]  += p*v0.x; acc[r][1]  += p*v0.y; acc[r][2]  += p*v0.z; acc[r][3]  += p*v0.w;
            acc[r][4]  += p*v1.x; acc[r][5]  += p*v1.y; acc[r][6]  += p*v1.z; acc[r][7]  += p*v1.w;
            acc[r][8]  += p*v2.x; acc[r][9]  += p*v2.y; acc[r][10] += p*v2.z; acc[r][11] += p*v2.w;
            acc[r][12] += p*v3.x; acc[r][13] += p*v3.y; acc[r][14] += p*v3.z; acc[r][15] += p*v3.w;
        }
        s[r] = sr;
    }

    // ---- epilogue: gamma*(acc/s) + residual ----
    float g = gamma_p[0];
    #pragma unroll
    for (int r = 0; r < ROWS; r++) {
        float inv = 1.0f / s[r];
        #pragma unroll
        for (int c = 0; c < C; c++) {
            float res = g*(acc[r][c]*inv)
                      + xres[(long)n*xn_s + (long)c*xc_s + (h0+r)*W + w];
            out[(long)n*on_s + (long)c*oc_s + (h0+r)*W + w] = res;
        }
    }
}

extern "C" void kernel_launch(void* const* d_in, const int* in_sizes, int n_in,
                              void* d_out, int out_size, void* d_ws, size_t ws_size,
                              hipStream_t stream) {
    const float* cost = (const float*)d_in[0];   // (1,16,24,96,192)
    const float* q_w  = (const float*)d_in[1];
    const float* q_b  = (const float*)d_in[2];
    const float* k_w  = (const float*)d_in[3];
    const float* k_b  = (const float*)d_in[4];
    const float* v_w  = (const float*)d_in[5];
    const float* v_b  = (const float*)d_in[6];
    const float* gamma= (const float*)d_in[7];
    float* out = (float*)d_out;
    float* ws  = (float*)d_ws;

    float2* Qp = (float2*)(ws + QP_OFF);
    float2* Kp = (float2*)(ws + KP_OFF);
    float4* Vp = (float4*)(ws + VP_OFF);
    float*  X1 = ws + X1_OFF;
    float*  cm = ws + CMAX_OFF;
    float*  rm = ws + RMAX_OFF;

    const int qkv_blocks  = (NIMG*PX)/256;   // 1728
    const int attn_blocks = NIMG*(H/ROWS);   // 768

    // pass 1: x = cost_volume, layout [c][n][h][w] (n stride PX, c stride 24*PX)
    qkv_kernel<<<qkv_blocks, 256, 0, stream>>>(
        cost, (long)PX, (long)NIMG*PX,
        q_w, q_b, k_w, k_b, v_w, v_b, Qp, Kp, Vp);
    stats_kernel<<<NIMG, 192, 0, stream>>>(Kp, cm, rm);
    attn_kernel<<<attn_blocks, 192, 0, stream>>>(
        Qp, Kp, Vp, cm, rm,
        cost, (long)PX, (long)NIMG*PX,
        X1, (long)C*PX, (long)PX,
        gamma);

    // pass 2: x = X1 ([n][c][h][w]); final out layout [c][n][h][w]
    qkv_kernel<<<qkv_blocks, 256, 0, stream>>>(
        X1, (long)C*PX, (long)PX,
        q_w, q_b, k_w, k_b, v_w, v_b, Qp, Kp, Vp);
    stats_kernel<<<NIMG, 192, 0, stream>>>(Kp, cm, rm);
    attn_kernel<<<attn_blocks, 192, 0, stream>>>(
        Qp, Kp, Vp, cm, rm,
        X1, (long)C*PX, (long)PX,
        out, (long)PX, (long)NIMG*PX,
        gamma);
}